// Round 5
// baseline (691.612 us; speedup 1.0000x reference)
//
#include <hip/hip_runtime.h>

#define D 128            // hidden dim
#define DOUT 10
#define CT_STRIDE 152    // C-tile LDS row stride in u16 (gemm_bn)
#define TSTR 136         // fused-kernel tile row stride in u16 (272 B, 16B-aligned)

typedef float f32x4 __attribute__((ext_vector_type(4)));
typedef __bf16 bf16x8 __attribute__((ext_vector_type(8)));
typedef unsigned short u16;

__device__ __forceinline__ float bf2f(u16 u) {
    return __uint_as_float(((unsigned int)u) << 16);
}
__device__ __forceinline__ u16 f2bf(float f) {
    unsigned int u = __float_as_uint(f);
    u += 0x7fffu + ((u >> 16) & 1u);
    return (u16)(u >> 16);
}

// ---------------- zero init (stats | gacc contiguous) ----------------
__global__ void k_zero(float4* __restrict__ p, int n4) {
    int i = blockIdx.x * 256 + threadIdx.x;
    if (i < n4) p[i] = make_float4(0.f, 0.f, 0.f, 0.f);
}

// ---------------- pre-swizzle W1/W2 into MFMA B-fragment order (once per call) -----
__global__ __launch_bounds__(256) void k_prepw(const float* __restrict__ W1,
                                               const float* __restrict__ W2,
                                               bf16x8* __restrict__ wswz, int L) {
    int b = blockIdx.x >> 3;
    const float* W = (b < L) ? (W1 + (size_t)b * D * D)
                             : (W2 + (size_t)(b - L) * D * D);
    bf16x8* o = wswz + (size_t)b * 2048;
    int idx = ((blockIdx.x & 7) << 8) + threadIdx.x;   // 0..2047
    int lane_s = idx & 63;
    int f = idx >> 6;
    int n = ((f >> 2) << 4) | (lane_s & 15);
    int kb = ((f & 3) << 5) | ((lane_s >> 4) << 3);
    bf16x8 fr;
#pragma unroll
    for (int j = 0; j < 8; ++j) fr[j] = (__bf16)W[(kb + j) * D + n];
    o[idx] = fr;
}

// ============ bucketing: 2048-edge chunks, deterministic two-level =================
__global__ __launch_bounds__(256) void k_hist(const int* __restrict__ dst,
                                              int* __restrict__ cnts, int E, int nb) {
    __shared__ int hist[1024];
    int tid = threadIdx.x;
    for (int i = tid; i < nb; i += 256) hist[i] = 0;
    __syncthreads();
    int e0 = blockIdx.x << 11;
    int e1 = e0 + 2048; if (e1 > E) e1 = E;
    for (int e = e0 + tid; e < e1; e += 256) atomicAdd(&hist[dst[e] >> 7], 1);
    __syncthreads();
    for (int i = tid; i < nb; i += 256) cnts[(blockIdx.x << 10) + i] = hist[i];
}

__global__ __launch_bounds__(256) void k_off(int* __restrict__ cnts,
                                             int* __restrict__ btot,
                                             int nbk, int nb) {
    int wave = threadIdx.x >> 6, lane = threadIdx.x & 63;
    int b = blockIdx.x * 4 + wave;
    if (b >= nb) return;
    int carry = 0;
    for (int base = 0; base < nbk; base += 64) {
        int idx = base + lane;
        int orig = (idx < nbk) ? cnts[(idx << 10) + b] : 0;
        int c = orig;
#pragma unroll
        for (int off = 1; off < 64; off <<= 1) {
            int v = __shfl_up(c, off);
            if (lane >= off) c += v;
        }
        if (idx < nbk) cnts[(idx << 10) + b] = carry + (c - orig);  // exclusive
        carry += __shfl(c, 63);
    }
    if (lane == 0) btot[b] = carry;
}

__global__ __launch_bounds__(256) void k_scat(const int* __restrict__ src,
                                              const int* __restrict__ dst,
                                              const int* __restrict__ cnts,
                                              int* __restrict__ pairs, int E, int nb) {
    __shared__ int lbase[1024];
    __shared__ int lcur[1024];
    int tid = threadIdx.x;
    for (int i = tid; i < nb; i += 256) {
        lbase[i] = cnts[(blockIdx.x << 10) + i];
        lcur[i] = 0;
    }
    __syncthreads();
    int e0 = blockIdx.x << 11;
    int e1 = e0 + 2048; if (e1 > E) e1 = E;
    for (int e = e0 + tid; e < e1; e += 256) {
        int d = dst[e];
        int b = d >> 7;
        int pos = lbase[b] + atomicAdd(&lcur[b], 1);
        if (pos < 4096) pairs[(b << 12) + pos] = (src[e] << 7) | (d & 127);
    }
}

// --------- one-time CSR: sort each bucket's edges by dst row, IN PLACE over pairs --
// Block b reads its entire pairs[b<<12 ..] region before overwriting it (all reads
// precede the post-scatter barrier); no cross-block aliasing. gmeta[b][0..127]=lcnt,
// [128..255]=inclusive loff. Hoists the per-layer phase-A rebuild out of k_aggemm.
__global__ __launch_bounds__(256) void k_csr(const int* __restrict__ bcnt,
                                             int* __restrict__ pairs,
                                             int* __restrict__ gmeta) {
    __shared__ int lcnt[128], loff[128], lcur[128];
    __shared__ int ledge[4096];
    int b = blockIdx.x, tid = threadIdx.x;
    if (tid < 128) lcnt[tid] = 0;
    __syncthreads();
    int cnt = bcnt[b]; if (cnt > 4096) cnt = 4096;
    const int* pb = pairs + ((size_t)b << 12);
    for (int e = tid; e < cnt; e += 256) atomicAdd(&lcnt[pb[e] & 127], 1);
    __syncthreads();
    if (tid < 128) loff[tid] = lcnt[tid];
    __syncthreads();
    for (int off = 1; off < 128; off <<= 1) {
        int v = 0;
        if (tid < 128 && tid >= off) v = loff[tid - off];
        __syncthreads();
        if (tid < 128) loff[tid] += v;
        __syncthreads();
    }
    if (tid < 128) lcur[tid] = loff[tid] - lcnt[tid];
    __syncthreads();
    for (int e = tid; e < cnt; e += 256) {
        int p = pb[e];
        int pos = atomicAdd(&lcur[p & 127], 1);
        ledge[pos] = p >> 7;
    }
    __syncthreads();   // all pairs reads done; safe to overwrite in place
    for (int e = tid; e < cnt; e += 256) pairs[((size_t)b << 12) + e] = ledge[e];
    if (tid < 128) {
        gmeta[(b << 8) + tid] = lcnt[tid];
        gmeta[(b << 8) + 128 + tid] = loff[tid];
    }
}

// ---------------- graph segment offsets: gptr[g] = lower_bound(gids, g) ------------
__global__ void k_gseg(const int* __restrict__ gids, int* __restrict__ gptr,
                       int M, int G) {
    int g = blockIdx.x * blockDim.x + threadIdx.x;
    if (g > G) return;
    if (g == 0) { gptr[0] = 0; return; }
    int lo = 0, hi = M;
    while (lo < hi) {
        int mid = (lo + hi) >> 1;
        if (gids[mid] < g) lo = mid + 1; else hi = mid;
    }
    gptr[g] = lo;
}

// ---------------- x fp32 -> bf16 (padded rows zeroed) ----------------
__global__ void k_cvt(const float* __restrict__ x, u16* __restrict__ o,
                      int M, int Mpad) {
    long e = ((long)blockIdx.x * 256 + threadIdx.x) * 4;
    if (e >= (long)Mpad * D) return;
    ushort4 r;
    if (e < (long)M * D) {
        float4 v = *(const float4*)(x + e);
        r.x = f2bf(v.x); r.y = f2bf(v.y); r.z = f2bf(v.z); r.w = f2bf(v.w);
    } else {
        r = make_ushort4(0, 0, 0, 0);
    }
    *(ushort4*)(o + e) = r;
}

// ======== FUSED aggregation + GEMM1(+bias) + BN1-stats =============================
// CSR is prebuilt by k_csr: phase A is now a 1 KB gmeta load; edge ids read straight
// from global (8 KB/bucket, L1/L2-resident). ~16 barriers removed vs round-4.
// NOTE: do NOT add VALU chains to the gather loop -- it is at the VGPR edge under
// (512,6); round-2/3's BN-fly variant spilled per-edge (+270 MB WRITE, 2.5x time).
__global__ __launch_bounds__(512, 6) void k_aggemm(
        const u16* __restrict__ h, const int* __restrict__ gedge,
        const int* __restrict__ gmeta, const float* __restrict__ eps, int layer,
        const bf16x8* __restrict__ wz, const float* __restrict__ bias,
        u16* __restrict__ O, float* __restrict__ stats, int M) {
    __shared__ u16 tile[128 * TSTR];           // pooled bf16 tile, then C-tile (34.8 KB)
    __shared__ int lcnt_s[128], loff_s[128];
    __shared__ float blds[D], psum[8 * D], psq[8 * D];
    int tid = threadIdx.x;
    int b = blockIdx.x;

    // ---- phase A (slim): CSR meta + bias ----
    if (tid < 128) {
        lcnt_s[tid] = gmeta[(b << 8) + tid];
        loff_s[tid] = gmeta[(b << 8) + 128 + tid];
    }
    if (tid >= 256 && tid < 256 + D) blds[tid - 256] = bias[tid - 256];
    __syncthreads();

    const int* ge = gedge + ((size_t)b << 12);

    // ---- phase B: gather into registers (8 rows per thread-group position) ----
    float e1 = 1.0f + eps[layer];
    int grp = tid >> 5;
    int c = (tid & 31) << 2;
    float r0[8], r1[8], r2[8], r3[8];
    for (int pass = 0; pass < 8; ++pass) {
        int row = (pass << 4) + grp;
        int node = (b << 7) + row;
        float a0 = 0.f, a1 = 0.f, a2 = 0.f, a3 = 0.f;
        if (node < M) {
            ushort4 sv = *(const ushort4*)(h + ((size_t)node << 7) + c);
            a0 = e1 * bf2f(sv.x); a1 = e1 * bf2f(sv.y);
            a2 = e1 * bf2f(sv.z); a3 = e1 * bf2f(sv.w);
            int dd = lcnt_s[row];
            int s = loff_s[row] - dd;
            int i = 0;
            for (; i + 8 <= dd; i += 8) {
                int n0 = ge[s + i],     n1 = ge[s + i + 1];
                int n2 = ge[s + i + 2], n3 = ge[s + i + 3];
                int n4 = ge[s + i + 4], n5 = ge[s + i + 5];
                int n6 = ge[s + i + 6], n7 = ge[s + i + 7];
                ushort4 u0 = *(const ushort4*)(h + ((size_t)n0 << 7) + c);
                ushort4 u1 = *(const ushort4*)(h + ((size_t)n1 << 7) + c);
                ushort4 u2 = *(const ushort4*)(h + ((size_t)n2 << 7) + c);
                ushort4 u3 = *(const ushort4*)(h + ((size_t)n3 << 7) + c);
                ushort4 u4 = *(const ushort4*)(h + ((size_t)n4 << 7) + c);
                ushort4 u5 = *(const ushort4*)(h + ((size_t)n5 << 7) + c);
                ushort4 u6 = *(const ushort4*)(h + ((size_t)n6 << 7) + c);
                ushort4 u7 = *(const ushort4*)(h + ((size_t)n7 << 7) + c);
                a0 += bf2f(u0.x) + bf2f(u1.x) + bf2f(u2.x) + bf2f(u3.x)
                    + bf2f(u4.x) + bf2f(u5.x) + bf2f(u6.x) + bf2f(u7.x);
                a1 += bf2f(u0.y) + bf2f(u1.y) + bf2f(u2.y) + bf2f(u3.y)
                    + bf2f(u4.y) + bf2f(u5.y) + bf2f(u6.y) + bf2f(u7.y);
                a2 += bf2f(u0.z) + bf2f(u1.z) + bf2f(u2.z) + bf2f(u3.z)
                    + bf2f(u4.z) + bf2f(u5.z) + bf2f(u6.z) + bf2f(u7.z);
                a3 += bf2f(u0.w) + bf2f(u1.w) + bf2f(u2.w) + bf2f(u3.w)
                    + bf2f(u4.w) + bf2f(u5.w) + bf2f(u6.w) + bf2f(u7.w);
            }
            for (; i + 4 <= dd; i += 4) {
                int n0 = ge[s + i],     n1 = ge[s + i + 1];
                int n2 = ge[s + i + 2], n3 = ge[s + i + 3];
                ushort4 u0 = *(const ushort4*)(h + ((size_t)n0 << 7) + c);
                ushort4 u1 = *(const ushort4*)(h + ((size_t)n1 << 7) + c);
                ushort4 u2 = *(const ushort4*)(h + ((size_t)n2 << 7) + c);
                ushort4 u3 = *(const ushort4*)(h + ((size_t)n3 << 7) + c);
                a0 += bf2f(u0.x) + bf2f(u1.x) + bf2f(u2.x) + bf2f(u3.x);
                a1 += bf2f(u0.y) + bf2f(u1.y) + bf2f(u2.y) + bf2f(u3.y);
                a2 += bf2f(u0.z) + bf2f(u1.z) + bf2f(u2.z) + bf2f(u3.z);
                a3 += bf2f(u0.w) + bf2f(u1.w) + bf2f(u2.w) + bf2f(u3.w);
            }
            for (; i < dd; ++i) {
                int n0 = ge[s + i];
                ushort4 u0 = *(const ushort4*)(h + ((size_t)n0 << 7) + c);
                a0 += bf2f(u0.x); a1 += bf2f(u0.y); a2 += bf2f(u0.z); a3 += bf2f(u0.w);
            }
        }
        r0[pass] = a0; r1[pass] = a1; r2[pass] = a2; r3[pass] = a3;
    }

    // ---- phase C: registers -> bf16 tile; tile -> A-frags; MFMA (B from global) ----
#pragma unroll
    for (int pass = 0; pass < 8; ++pass) {
        int row = (pass << 4) + grp;
        ushort4 v;
        v.x = f2bf(r0[pass]); v.y = f2bf(r1[pass]);
        v.z = f2bf(r2[pass]); v.w = f2bf(r3[pass]);
        *(ushort4*)&tile[row * TSTR + c] = v;
    }
    __syncthreads();

    int wave = tid >> 6, lane = tid & 63;
    int m = lane & 15, quad = lane >> 4;
    f32x4 z = {0.f, 0.f, 0.f, 0.f};
    f32x4 acc[8];
#pragma unroll
    for (int t = 0; t < 8; ++t) acc[t] = z;
    const bf16x8* wlp = wz + lane;   // fragment idx: ((t<<2)|kc)<<6 | lane
#pragma unroll
    for (int kc = 0; kc < 4; ++kc) {
        bf16x8 af = *(const bf16x8*)&tile[(wave * 16 + m) * TSTR + (kc << 5) + (quad << 3)];
        bf16x8 w0 = wlp[(0  | kc) << 6];
        bf16x8 w1 = wlp[(4  | kc) << 6];
        bf16x8 w2 = wlp[(8  | kc) << 6];
        bf16x8 w3 = wlp[(12 | kc) << 6];
        acc[0] = __builtin_amdgcn_mfma_f32_16x16x32_bf16(af, w0, acc[0], 0, 0, 0);
        acc[1] = __builtin_amdgcn_mfma_f32_16x16x32_bf16(af, w1, acc[1], 0, 0, 0);
        acc[2] = __builtin_amdgcn_mfma_f32_16x16x32_bf16(af, w2, acc[2], 0, 0, 0);
        acc[3] = __builtin_amdgcn_mfma_f32_16x16x32_bf16(af, w3, acc[3], 0, 0, 0);
        w0 = wlp[(16 | kc) << 6];
        w1 = wlp[(20 | kc) << 6];
        w2 = wlp[(24 | kc) << 6];
        w3 = wlp[(28 | kc) << 6];
        acc[4] = __builtin_amdgcn_mfma_f32_16x16x32_bf16(af, w0, acc[4], 0, 0, 0);
        acc[5] = __builtin_amdgcn_mfma_f32_16x16x32_bf16(af, w1, acc[5], 0, 0, 0);
        acc[6] = __builtin_amdgcn_mfma_f32_16x16x32_bf16(af, w2, acc[6], 0, 0, 0);
        acc[7] = __builtin_amdgcn_mfma_f32_16x16x32_bf16(af, w3, acc[7], 0, 0, 0);
    }
    __syncthreads();   // done reading tile; reuse as C-tile

    // ---- phase D: epilogue (bias, stats, C via LDS, coalesced stores) ----
    int lr0 = wave * 16 + (quad << 2);
    int gr0 = (b << 7) + lr0;
#pragma unroll
    for (int t = 0; t < 8; ++t) {
        int cch = (t << 4) | m;
        float bc = blds[cch];
        float s = 0.f, q = 0.f;
#pragma unroll
        for (int r = 0; r < 4; ++r) {
            float v = acc[t][r] + bc;
            tile[(lr0 + r) * TSTR + cch] = f2bf(v);
            if (gr0 + r < M) { s += v; q += v * v; }
        }
        s += __shfl_xor(s, 16); s += __shfl_xor(s, 32);
        q += __shfl_xor(q, 16); q += __shfl_xor(q, 32);
        if (quad == 0) { psum[wave * D + cch] = s; psq[wave * D + cch] = q; }
    }
    __syncthreads();

    int mrow = M - (b << 7);
#pragma unroll
    for (int i = 0; i < 4; ++i) {
        int idx = (i << 9) + tid;
        int row = idx >> 4, ch8 = (idx & 15) << 3;
        if (row < mrow) {
            float4 v = *(const float4*)&tile[row * TSTR + ch8];
            *(float4*)(O + (((size_t)(b << 7) + row) << 7) + ch8) = v;
        }
    }
    if (tid < D) {
        float s = 0.f, q = 0.f;
#pragma unroll
        for (int w = 0; w < 8; ++w) { s += psum[w * D + tid]; q += psq[w * D + tid]; }
        float* st = stats + ((b & 7) << 8);
        atomicAdd(&st[tid], s);
        atomicAdd(&st[D + tid], q);
    }
}

// ---------------- GEMM2: BN1+ReLU on the fly -> @W + b, in-place, + stats2 ---------
// XCD-aligned remap: aggemm's bucket b ran on XCD b%8 (round-robin dispatch), its
// y1 tile sits dirty in that XCD's L2. Map blockIdx -> (bucket,half) preserving
// bucket%8 == blockIdx%8 so the A-read is a local-L2 hit. Grid = 2*ceil8(nb);
// phantom buckets (b >= nb) return early.
__global__ __launch_bounds__(256, 4) void k_gemm_bn(
        u16* __restrict__ A, const bf16x8* __restrict__ wz,
        const float* __restrict__ bias, const float* __restrict__ stats_in,
        const float* __restrict__ gamma, const float* __restrict__ beta,
        float* __restrict__ stats_out, float invM, int M, int nbuck) {
    int j = blockIdx.x;
    int x = j & 7, n = j >> 3;
    int half = n & 1, q = n >> 1;
    int b = (q << 3) + x;
    if (b >= nbuck) return;
    int rb = (b << 7) + (half << 6);

    __shared__ union { bf16x8 w[2048]; u16 c[64 * CT_STRIDE]; } sh;
    __shared__ float blds[D], s_sc[D], s_sh[D], psum[4 * D], psq[4 * D];
    int tid = threadIdx.x;
    int wave = tid >> 6, lane = tid & 63;
    int m = lane & 15, quad = lane >> 4;
    int row0 = rb + wave * 16;

    const u16* ap = A + (size_t)(row0 + m) * D + (quad << 3);
    ushort4 p[4][2];
#pragma unroll
    for (int kc = 0; kc < 4; ++kc) {
        p[kc][0] = *(const ushort4*)(ap + (kc << 5));
        p[kc][1] = *(const ushort4*)(ap + (kc << 5) + 4);
    }

    for (int i = tid; i < 2048; i += 256) sh.w[i] = wz[i];
    if (tid < D) {
        float s = 0.f, qq = 0.f;
#pragma unroll
        for (int r = 0; r < 8; ++r) {
            s += stats_in[(r << 8) + tid];
            qq += stats_in[(r << 8) + D + tid];
        }
        float mean = s * invM;
        float var = qq * invM - mean * mean;
        float sc = rsqrtf(var + 1e-5f) * gamma[tid];
        s_sc[tid] = sc;
        s_sh[tid] = beta[tid] - mean * sc;
        blds[tid] = bias[tid];
    }
    __syncthreads();

    f32x4 z = {0.f, 0.f, 0.f, 0.f};
    f32x4 acc[8];
#pragma unroll
    for (int t = 0; t < 8; ++t) acc[t] = z;

#pragma unroll
    for (int kc = 0; kc < 4; ++kc) {
        int kb = (kc << 5) | (quad << 3);
        float4 c0 = *(const float4*)&s_sc[kb];
        float4 c1 = *(const float4*)&s_sc[kb + 4];
        float4 h0 = *(const float4*)&s_sh[kb];
        float4 h1 = *(const float4*)&s_sh[kb + 4];
        ushort4 p0 = p[kc][0], p1 = p[kc][1];
        bf16x8 af;
        af[0] = (__bf16)fmaxf(0.f, fmaf(bf2f(p0.x), c0.x, h0.x));
        af[1] = (__bf16)fmaxf(0.f, fmaf(bf2f(p0.y), c0.y, h0.y));
        af[2] = (__bf16)fmaxf(0.f, fmaf(bf2f(p0.z), c0.z, h0.z));
        af[3] = (__bf16)fmaxf(0.f, fmaf(bf2f(p0.w), c0.w, h0.w));
        af[4] = (__bf16)fmaxf(0.f, fmaf(bf2f(p1.x), c1.x, h1.x));
        af[5] = (__bf16)fmaxf(0.f, fmaf(bf2f(p1.y), c1.y, h1.y));
        af[6] = (__bf16)fmaxf(0.f, fmaf(bf2f(p1.z), c1.z, h1.z));
        af[7] = (__bf16)fmaxf(0.f, fmaf(bf2f(p1.w), c1.w, h1.w));
#pragma unroll
        for (int t = 0; t < 8; ++t)
            acc[t] = __builtin_amdgcn_mfma_f32_16x16x32_bf16(
                af, sh.w[(((t << 2) | kc) << 6) | lane], acc[t], 0, 0, 0);
    }
    __syncthreads();

    int lr0 = wave * 16 + (quad << 2);
    int gr0 = rb + lr0;
#pragma unroll
    for (int t = 0; t < 8; ++t) {
        int cch = (t << 4) | m;
        float bc = blds[cch];
        float s = 0.f, qq = 0.f;
#pragma unroll
        for (int r = 0; r < 4; ++r) {
            float v = acc[t][r] + bc;
            sh.c[(lr0 + r) * CT_STRIDE + cch] = f2bf(v);
            if (gr0 + r < M) { s += v; qq += v * v; }
        }
        s += __shfl_xor(s, 16); s += __shfl_xor(s, 32);
        qq += __shfl_xor(qq, 16); qq += __shfl_xor(qq, 32);
        if (quad == 0) { psum[wave * D + cch] = s; psq[wave * D + cch] = qq; }
    }
    __syncthreads();

    int mrow = M - rb;
#pragma unroll
    for (int i = 0; i < 4; ++i) {
        int idx = (i << 8) + tid;
        int row = idx >> 4, ch8 = (idx & 15) << 3;
        if (row < mrow) {
            float4 v = *(const float4*)&sh.c[row * CT_STRIDE + ch8];
            *(float4*)(A + ((size_t)(rb + row) << 7) + ch8) = v;
        }
    }
    if (tid < D) {
        float s = psum[tid] + psum[D + tid] + psum[2 * D + tid] + psum[3 * D + tid];
        float qq = psq[tid] + psq[D + tid] + psq[2 * D + tid] + psq[3 * D + tid];
        float* st = stats_out + (x << 8);
        atomicAdd(&st[tid], s);
        atomicAdd(&st[D + tid], qq);
    }
}

// ---------- BN2+ReLU -> h (bufH), + per-graph pooling with ZERO atomics ------------
__device__ __forceinline__ void bnrow(const u16* __restrict__ y,
                                      u16* __restrict__ hout, size_t row, int c,
                                      float4 sc4, float4 sh4, int writeh,
                                      float& a0, float& a1, float& a2, float& a3) {
    ushort4 u = *(const ushort4*)(y + (row << 7) + c);
    float h0 = fmaxf(0.f, fmaf(bf2f(u.x), sc4.x, sh4.x));
    float h1 = fmaxf(0.f, fmaf(bf2f(u.y), sc4.y, sh4.y));
    float h2 = fmaxf(0.f, fmaf(bf2f(u.z), sc4.z, sh4.z));
    float h3 = fmaxf(0.f, fmaf(bf2f(u.w), sc4.w, sh4.w));
    if (writeh) {
        ushort4 o;
        o.x = f2bf(h0); o.y = f2bf(h1); o.z = f2bf(h2); o.w = f2bf(h3);
        *(ushort4*)(hout + (row << 7) + c) = o;
    }
    a0 += h0; a1 += h1; a2 += h2; a3 += h3;
}

template<int WRITEH>
__global__ __launch_bounds__(512) void k_bnpool(
        const u16* __restrict__ y, const float* __restrict__ stats,
        const float* __restrict__ gamma, const float* __restrict__ beta,
        const int* __restrict__ gptr, const float* __restrict__ fw,
        int layer, u16* __restrict__ hout, float* __restrict__ gacc, float invM) {
    __shared__ float s_sc[D], s_sh[D];
    __shared__ float red[16 * D];
    int t = threadIdx.x;
    if (t < D) {
        float s = 0.f, q = 0.f;
#pragma unroll
        for (int r = 0; r < 8; ++r) {
            s += stats[(r << 8) + t];
            q += stats[(r << 8) + D + t];
        }
        float mean = s * invM;
        float sv = rsqrtf(q * invM - mean * mean + 1e-5f) * gamma[t];
        s_sc[t] = sv;
        s_sh[t] = beta[t] - mean * sv;
    }
    __syncthreads();

    int g = blockIdx.x;
    int n0 = gptr[g], n1 = gptr[g + 1];
    int c = (t & 31) << 2;
    int rg = t >> 5;                    // 16 row-groups, rows stride 16
    float4 sc4 = *(const float4*)&s_sc[c];
    float4 sh4 = *(const float4*)&s_sh[c];

    float a0 = 0.f, a1 = 0.f, a2 = 0.f, a3 = 0.f;
    int r = n0 + rg;
    for (; r + 48 < n1; r += 64) {      // 4 rows in flight per thread
        bnrow(y, hout, (size_t)r,        c, sc4, sh4, WRITEH, a0, a1, a2, a3);
        bnrow(y, hout, (size_t)(r + 16), c, sc4, sh4, WRITEH, a0, a1, a2, a3);
        bnrow(y, hout, (size_t)(r + 32), c, sc4, sh4, WRITEH, a0, a1, a2, a3);
        bnrow(y, hout, (size_t)(r + 48), c, sc4, sh4, WRITEH, a0, a1, a2, a3);
    }
    for (; r < n1; r += 16)
        bnrow(y, hout, (size_t)r, c, sc4, sh4, WRITEH, a0, a1, a2, a3);

    *(float4*)&red[rg * D + c] = make_float4(a0, a1, a2, a3);
    __syncthreads();

    if (t < D) {
        float s = 0.f;
#pragma unroll
        for (int w = 0; w < 16; ++w) s += red[w * D + t];
        gacc[((size_t)g << 7) + t] += fw[layer] * s;
    }
}

// ---------------- final: out = gacc(Gx128) @ Wp(128x10) + bp ----------------
__global__ void k_final(const float* __restrict__ gacc, const float* __restrict__ Wp,
                        const float* __restrict__ bp, float* __restrict__ out) {
    __shared__ float w[D * DOUT];
    __shared__ float bb[DOUT];
    int t = threadIdx.x;
    for (int i = t; i < D * DOUT; i += blockDim.x) w[i] = Wp[i];
    if (t < DOUT) bb[t] = bp[t];
    __syncthreads();
    float acc[DOUT];
#pragma unroll
    for (int o = 0; o < DOUT; ++o) acc[o] = bb[o];
    for (int k = 0; k < D; ++k) {
        float a = gacc[(size_t)t * D + k];
#pragma unroll
        for (int o = 0; o < DOUT; ++o) acc[o] += a * w[k * DOUT + o];
    }
#pragma unroll
    for (int o = 0; o < DOUT; ++o) out[(size_t)t * DOUT + o] = acc[o];
}

extern "C" void kernel_launch(void* const* d_in, const int* in_sizes, int n_in,
                              void* d_out, int out_size, void* d_ws, size_t ws_size,
                              hipStream_t stream) {
    const float* x    = (const float*)d_in[0];
    const int* esrc   = (const int*)d_in[1];
    const int* edst   = (const int*)d_in[2];
    const int* gids   = (const int*)d_in[3];
    const float* eps  = (const float*)d_in[4];
    const float* fw   = (const float*)d_in[5];
    const float* W1   = (const float*)d_in[6];
    const float* b1   = (const float*)d_in[7];
    const float* g1   = (const float*)d_in[8];
    const float* bt1  = (const float*)d_in[9];
    const float* W2   = (const float*)d_in[10];
    const float* b2   = (const float*)d_in[11];
    const float* g2   = (const float*)d_in[12];
    const float* bt2  = (const float*)d_in[13];
    const float* Wp   = (const float*)d_in[14];
    const float* bp   = (const float*)d_in[15];
    float* out        = (float*)d_out;

    const int M = in_sizes[3];     // 100000 nodes
    const int E = in_sizes[1];     // 1600000 edges
    const int L = in_sizes[4];     // 4 layers
    const int G = out_size / DOUT; // 256 graphs
    const int nb  = (M + 127) >> 7;           // buckets of 128 dst nodes (782)
    const int Mpad = nb << 7;
    const int nbk = (E + 2047) >> 11;         // 2K-edge chunks (782)
    const float invM = 1.0f / (float)M;

    char* ws = (char*)d_ws;
    u16* bufT  = (u16*)ws;  ws += (size_t)Mpad * D * 2;   // y1 -> y2 (in-place MLP)
    u16* bufH  = (u16*)ws;  ws += (size_t)Mpad * D * 2;   // hidden bf16 (gather src)
    int* pairs = (int*)ws;  ws += (size_t)nb * 4096 * 4;  // packed pairs -> CSR edges
    int* cnts  = (int*)ws;  ws += (size_t)nbk * 1024 * 4; // per-(chunk,bucket) bases
    int* btot  = (int*)ws;  ws += 1024 * 4;               // bucket totals
    int* gptr  = (int*)ws;  ws += 512 * 4;                // graph segment offsets
    int* gmeta = (int*)ws;  ws += (size_t)nb * 256 * 4;   // per-bucket lcnt|loff
    bf16x8* wswz = (bf16x8*)ws; ws += (size_t)2 * L * 2048 * 16;  // swizzled W
    // contiguous zero region: stats (8 replicas) | gacc
    float* stats = (float*)ws; ws += (size_t)L * 4096 * 4;
    float* gacc  = (float*)ws; ws += (size_t)G * D * 4;

    int zbytes = L * 4096 * 4 + G * D * 4;
    int n4 = zbytes / 16;
    k_zero<<<(n4 + 255) / 256, 256, 0, stream>>>((float4*)stats, n4);

    k_prepw<<<2 * L * 8, 256, 0, stream>>>(W1, W2, wswz, L);
    k_hist<<<nbk, 256, 0, stream>>>(edst, cnts, E, nb);
    k_off<<<(nb + 3) / 4, 256, 0, stream>>>(cnts, btot, nbk, nb);
    k_scat<<<nbk, 256, 0, stream>>>(esrc, edst, cnts, pairs, E, nb);
    k_csr<<<nb, 256, 0, stream>>>(btot, pairs, gmeta);   // in-place CSR sort
    k_gseg<<<1, 512, 0, stream>>>(gids, gptr, M, G);
    k_cvt<<<(Mpad * (D / 4) + 255) / 256, 256, 0, stream>>>(x, bufH, M, Mpad);

    int nbR = (nb + 7) & ~7;          // XCD-aligned gemm_bn grid: 2 halves per bucket
    for (int l = 0; l < L; ++l) {
        float* st1 = stats + (size_t)l * 4096;
        float* st2 = st1 + 2048;
        k_aggemm<<<nb, 512, 0, stream>>>(bufH, pairs, gmeta, eps, l,
                                         wswz + (size_t)l * 2048, b1 + (size_t)l * D,
                                         bufT, st1, M);
        k_gemm_bn<<<nbR * 2, 256, 0, stream>>>(bufT, wswz + (size_t)(L + l) * 2048,
                                               b2 + (size_t)l * D, st1,
                                               g1 + (size_t)l * D, bt1 + (size_t)l * D,
                                               st2, invM, M, nb);
        if (l < L - 1)
            k_bnpool<1><<<G, 512, 0, stream>>>(bufT, st2, g2 + (size_t)l * D,
                                               bt2 + (size_t)l * D, gptr, fw, l,
                                               bufH, gacc, invM);
        else
            k_bnpool<0><<<G, 512, 0, stream>>>(bufT, st2, g2 + (size_t)l * D,
                                               bt2 + (size_t)l * D, gptr, fw, l,
                                               bufH, gacc, invM);
    }
    k_final<<<1, G, 0, stream>>>(gacc, Wp, bp, out);
}

// Round 6
// 645.124 us; speedup vs baseline: 1.0721x; 1.0721x over previous
//
#include <hip/hip_runtime.h>

#define D 128            // hidden dim
#define DOUT 10
#define CT_STRIDE 152    // C-tile LDS row stride in u16 (gemm_bn)
#define TSTR 136         // fused-kernel tile row stride in u16 (272 B, 16B-aligned)

typedef float f32x4 __attribute__((ext_vector_type(4)));
typedef __bf16 bf16x8 __attribute__((ext_vector_type(8)));
typedef unsigned short u16;

__device__ __forceinline__ float bf2f(u16 u) {
    return __uint_as_float(((unsigned int)u) << 16);
}
__device__ __forceinline__ u16 f2bf(float f) {
    unsigned int u = __float_as_uint(f);
    u += 0x7fffu + ((u >> 16) & 1u);
    return (u16)(u >> 16);
}

// ---------------- zero init (stats | gacc contiguous) ----------------
__global__ void k_zero(float4* __restrict__ p, int n4) {
    int i = blockIdx.x * 256 + threadIdx.x;
    if (i < n4) p[i] = make_float4(0.f, 0.f, 0.f, 0.f);
}

// ---------------- pre-swizzle W1/W2 into MFMA B-fragment order (once per call) -----
__global__ __launch_bounds__(256) void k_prepw(const float* __restrict__ W1,
                                               const float* __restrict__ W2,
                                               bf16x8* __restrict__ wswz, int L) {
    int b = blockIdx.x >> 3;
    const float* W = (b < L) ? (W1 + (size_t)b * D * D)
                             : (W2 + (size_t)(b - L) * D * D);
    bf16x8* o = wswz + (size_t)b * 2048;
    int idx = ((blockIdx.x & 7) << 8) + threadIdx.x;   // 0..2047
    int lane_s = idx & 63;
    int f = idx >> 6;
    int n = ((f >> 2) << 4) | (lane_s & 15);
    int kb = ((f & 3) << 5) | ((lane_s >> 4) << 3);
    bf16x8 fr;
#pragma unroll
    for (int j = 0; j < 8; ++j) fr[j] = (__bf16)W[(kb + j) * D + n];
    o[idx] = fr;
}

// ============ bucketing: 2048-edge chunks, deterministic two-level =================
__global__ __launch_bounds__(256) void k_hist(const int* __restrict__ dst,
                                              int* __restrict__ cnts, int E, int nb) {
    __shared__ int hist[1024];
    int tid = threadIdx.x;
    for (int i = tid; i < nb; i += 256) hist[i] = 0;
    __syncthreads();
    int e0 = blockIdx.x << 11;
    int e1 = e0 + 2048; if (e1 > E) e1 = E;
    for (int e = e0 + tid; e < e1; e += 256) atomicAdd(&hist[dst[e] >> 7], 1);
    __syncthreads();
    for (int i = tid; i < nb; i += 256) cnts[(blockIdx.x << 10) + i] = hist[i];
}

__global__ __launch_bounds__(256) void k_off(int* __restrict__ cnts,
                                             int* __restrict__ btot,
                                             int nbk, int nb) {
    int wave = threadIdx.x >> 6, lane = threadIdx.x & 63;
    int b = blockIdx.x * 4 + wave;
    if (b >= nb) return;
    int carry = 0;
    for (int base = 0; base < nbk; base += 64) {
        int idx = base + lane;
        int orig = (idx < nbk) ? cnts[(idx << 10) + b] : 0;
        int c = orig;
#pragma unroll
        for (int off = 1; off < 64; off <<= 1) {
            int v = __shfl_up(c, off);
            if (lane >= off) c += v;
        }
        if (idx < nbk) cnts[(idx << 10) + b] = carry + (c - orig);  // exclusive
        carry += __shfl(c, 63);
    }
    if (lane == 0) btot[b] = carry;
}

__global__ __launch_bounds__(256) void k_scat(const int* __restrict__ src,
                                              const int* __restrict__ dst,
                                              const int* __restrict__ cnts,
                                              int* __restrict__ pairs, int E, int nb) {
    __shared__ int lbase[1024];
    __shared__ int lcur[1024];
    int tid = threadIdx.x;
    for (int i = tid; i < nb; i += 256) {
        lbase[i] = cnts[(blockIdx.x << 10) + i];
        lcur[i] = 0;
    }
    __syncthreads();
    int e0 = blockIdx.x << 11;
    int e1 = e0 + 2048; if (e1 > E) e1 = E;
    for (int e = e0 + tid; e < e1; e += 256) {
        int d = dst[e];
        int b = d >> 7;
        int pos = lbase[b] + atomicAdd(&lcur[b], 1);
        if (pos < 4096) pairs[(b << 12) + pos] = (src[e] << 7) | (d & 127);
    }
}

// --------- one-time CSR: sort each bucket's edges by dst row, IN PLACE over pairs --
// gmeta[b][0..127]=lcnt, [128..255]=inclusive loff. Hoists the per-layer phase-A
// rebuild out of k_aggemm.
__global__ __launch_bounds__(256) void k_csr(const int* __restrict__ bcnt,
                                             int* __restrict__ pairs,
                                             int* __restrict__ gmeta) {
    __shared__ int lcnt[128], loff[128], lcur[128];
    __shared__ int ledge[4096];
    int b = blockIdx.x, tid = threadIdx.x;
    if (tid < 128) lcnt[tid] = 0;
    __syncthreads();
    int cnt = bcnt[b]; if (cnt > 4096) cnt = 4096;
    const int* pb = pairs + ((size_t)b << 12);
    for (int e = tid; e < cnt; e += 256) atomicAdd(&lcnt[pb[e] & 127], 1);
    __syncthreads();
    if (tid < 128) loff[tid] = lcnt[tid];
    __syncthreads();
    for (int off = 1; off < 128; off <<= 1) {
        int v = 0;
        if (tid < 128 && tid >= off) v = loff[tid - off];
        __syncthreads();
        if (tid < 128) loff[tid] += v;
        __syncthreads();
    }
    if (tid < 128) lcur[tid] = loff[tid] - lcnt[tid];
    __syncthreads();
    for (int e = tid; e < cnt; e += 256) {
        int p = pb[e];
        int pos = atomicAdd(&lcur[p & 127], 1);
        ledge[pos] = p >> 7;
    }
    __syncthreads();   // all pairs reads done; safe to overwrite in place
    for (int e = tid; e < cnt; e += 256) pairs[((size_t)b << 12) + e] = ledge[e];
    if (tid < 128) {
        gmeta[(b << 8) + tid] = lcnt[tid];
        gmeta[(b << 8) + 128 + tid] = loff[tid];
    }
}

// ---------------- graph segment offsets: gptr[g] = lower_bound(gids, g) ------------
__global__ void k_gseg(const int* __restrict__ gids, int* __restrict__ gptr,
                       int M, int G) {
    int g = blockIdx.x * blockDim.x + threadIdx.x;
    if (g > G) return;
    if (g == 0) { gptr[0] = 0; return; }
    int lo = 0, hi = M;
    while (lo < hi) {
        int mid = (lo + hi) >> 1;
        if (gids[mid] < g) lo = mid + 1; else hi = mid;
    }
    gptr[g] = lo;
}

// ---------------- x fp32 -> bf16 (padded rows zeroed) ----------------
__global__ void k_cvt(const float* __restrict__ x, u16* __restrict__ o,
                      int M, int Mpad) {
    long e = ((long)blockIdx.x * 256 + threadIdx.x) * 4;
    if (e >= (long)Mpad * D) return;
    ushort4 r;
    if (e < (long)M * D) {
        float4 v = *(const float4*)(x + e);
        r.x = f2bf(v.x); r.y = f2bf(v.y); r.z = f2bf(v.z); r.w = f2bf(v.w);
    } else {
        r = make_ushort4(0, 0, 0, 0);
    }
    *(ushort4*)(o + e) = r;
}

// ======== FUSED aggregation + GEMM1(+bias) + BN1-stats =============================
// CSR prebuilt by k_csr; phase A = coalesced 16 KB edge-list copy global->LDS +
// 1 KB meta (1 barrier, no LDS atomics). Phase B reads edges via LDS broadcast
// (round-5 lesson: global edge reads add ~150 cyc to the gather dependency chain).
// NOTE: do NOT add VALU chains to the gather loop -- it is at the VGPR edge under
// (512,6); round-2/3's BN-fly variant spilled per-edge (+270 MB WRITE, 2.5x time).
__global__ __launch_bounds__(512, 6) void k_aggemm(
        const u16* __restrict__ h, const int* __restrict__ gedge,
        const int* __restrict__ gmeta, const int* __restrict__ bcnt,
        const float* __restrict__ eps, int layer,
        const bf16x8* __restrict__ wz, const float* __restrict__ bias,
        u16* __restrict__ O, float* __restrict__ stats, int M) {
    __shared__ union UA {
        struct { int lcnt[128]; int loff[128]; int ledge[4096]; } csr;
        u16 tile[128 * TSTR];   // pooled bf16 tile, then C-tile (34.8 KB)
    } shA;
    __shared__ float blds[D], psum[8 * D], psq[8 * D];
    int tid = threadIdx.x;
    int b = blockIdx.x;

    // ---- phase A (slim): meta load + coalesced edge-list copy into LDS ----
    if (tid < 128) shA.csr.lcnt[tid] = gmeta[(b << 8) + tid];
    else if (tid < 256) shA.csr.loff[tid - 128] = gmeta[(b << 8) + tid];
    else if (tid < 256 + D) blds[tid - 256] = bias[tid - 256];
    int cnt = bcnt[b]; if (cnt > 4096) cnt = 4096;
    const int4* ge4 = (const int4*)(gedge + ((size_t)b << 12));
    int n4c = (cnt + 3) >> 2;
    for (int i = tid; i < n4c; i += 512) ((int4*)shA.csr.ledge)[i] = ge4[i];
    __syncthreads();

    // ---- phase B: gather into registers (8 rows per thread-group position) ----
    float e1 = 1.0f + eps[layer];
    int grp = tid >> 5;
    int c = (tid & 31) << 2;
    float r0[8], r1[8], r2[8], r3[8];
    for (int pass = 0; pass < 8; ++pass) {
        int row = (pass << 4) + grp;
        int node = (b << 7) + row;
        float a0 = 0.f, a1 = 0.f, a2 = 0.f, a3 = 0.f;
        if (node < M) {
            ushort4 sv = *(const ushort4*)(h + ((size_t)node << 7) + c);
            a0 = e1 * bf2f(sv.x); a1 = e1 * bf2f(sv.y);
            a2 = e1 * bf2f(sv.z); a3 = e1 * bf2f(sv.w);
            int dd = shA.csr.lcnt[row];
            int s = shA.csr.loff[row] - dd;
            int i = 0;
            for (; i + 8 <= dd; i += 8) {
                int n0 = shA.csr.ledge[s + i],     n1 = shA.csr.ledge[s + i + 1];
                int n2 = shA.csr.ledge[s + i + 2], n3 = shA.csr.ledge[s + i + 3];
                int n4 = shA.csr.ledge[s + i + 4], n5 = shA.csr.ledge[s + i + 5];
                int n6 = shA.csr.ledge[s + i + 6], n7 = shA.csr.ledge[s + i + 7];
                ushort4 u0 = *(const ushort4*)(h + ((size_t)n0 << 7) + c);
                ushort4 u1 = *(const ushort4*)(h + ((size_t)n1 << 7) + c);
                ushort4 u2 = *(const ushort4*)(h + ((size_t)n2 << 7) + c);
                ushort4 u3 = *(const ushort4*)(h + ((size_t)n3 << 7) + c);
                ushort4 u4 = *(const ushort4*)(h + ((size_t)n4 << 7) + c);
                ushort4 u5 = *(const ushort4*)(h + ((size_t)n5 << 7) + c);
                ushort4 u6 = *(const ushort4*)(h + ((size_t)n6 << 7) + c);
                ushort4 u7 = *(const ushort4*)(h + ((size_t)n7 << 7) + c);
                a0 += bf2f(u0.x) + bf2f(u1.x) + bf2f(u2.x) + bf2f(u3.x)
                    + bf2f(u4.x) + bf2f(u5.x) + bf2f(u6.x) + bf2f(u7.x);
                a1 += bf2f(u0.y) + bf2f(u1.y) + bf2f(u2.y) + bf2f(u3.y)
                    + bf2f(u4.y) + bf2f(u5.y) + bf2f(u6.y) + bf2f(u7.y);
                a2 += bf2f(u0.z) + bf2f(u1.z) + bf2f(u2.z) + bf2f(u3.z)
                    + bf2f(u4.z) + bf2f(u5.z) + bf2f(u6.z) + bf2f(u7.z);
                a3 += bf2f(u0.w) + bf2f(u1.w) + bf2f(u2.w) + bf2f(u3.w)
                    + bf2f(u4.w) + bf2f(u5.w) + bf2f(u6.w) + bf2f(u7.w);
            }
            for (; i + 4 <= dd; i += 4) {
                int n0 = shA.csr.ledge[s + i],     n1 = shA.csr.ledge[s + i + 1];
                int n2 = shA.csr.ledge[s + i + 2], n3 = shA.csr.ledge[s + i + 3];
                ushort4 u0 = *(const ushort4*)(h + ((size_t)n0 << 7) + c);
                ushort4 u1 = *(const ushort4*)(h + ((size_t)n1 << 7) + c);
                ushort4 u2 = *(const ushort4*)(h + ((size_t)n2 << 7) + c);
                ushort4 u3 = *(const ushort4*)(h + ((size_t)n3 << 7) + c);
                a0 += bf2f(u0.x) + bf2f(u1.x) + bf2f(u2.x) + bf2f(u3.x);
                a1 += bf2f(u0.y) + bf2f(u1.y) + bf2f(u2.y) + bf2f(u3.y);
                a2 += bf2f(u0.z) + bf2f(u1.z) + bf2f(u2.z) + bf2f(u3.z);
                a3 += bf2f(u0.w) + bf2f(u1.w) + bf2f(u2.w) + bf2f(u3.w);
            }
            for (; i < dd; ++i) {
                int n0 = shA.csr.ledge[s + i];
                ushort4 u0 = *(const ushort4*)(h + ((size_t)n0 << 7) + c);
                a0 += bf2f(u0.x); a1 += bf2f(u0.y); a2 += bf2f(u0.z); a3 += bf2f(u0.w);
            }
        }
        r0[pass] = a0; r1[pass] = a1; r2[pass] = a2; r3[pass] = a3;
    }
    __syncthreads();   // CSR no longer needed; union flips to tile

    // ---- phase C: registers -> bf16 tile; tile -> A-frags; MFMA (B from global) ----
#pragma unroll
    for (int pass = 0; pass < 8; ++pass) {
        int row = (pass << 4) + grp;
        ushort4 v;
        v.x = f2bf(r0[pass]); v.y = f2bf(r1[pass]);
        v.z = f2bf(r2[pass]); v.w = f2bf(r3[pass]);
        *(ushort4*)&shA.tile[row * TSTR + c] = v;
    }
    __syncthreads();

    int wave = tid >> 6, lane = tid & 63;
    int m = lane & 15, quad = lane >> 4;
    f32x4 z = {0.f, 0.f, 0.f, 0.f};
    f32x4 acc[8];
#pragma unroll
    for (int t = 0; t < 8; ++t) acc[t] = z;
    const bf16x8* wlp = wz + lane;   // fragment idx: ((t<<2)|kc)<<6 | lane
#pragma unroll
    for (int kc = 0; kc < 4; ++kc) {
        bf16x8 af = *(const bf16x8*)&shA.tile[(wave * 16 + m) * TSTR + (kc << 5) + (quad << 3)];
        bf16x8 w0 = wlp[(0  | kc) << 6];
        bf16x8 w1 = wlp[(4  | kc) << 6];
        bf16x8 w2 = wlp[(8  | kc) << 6];
        bf16x8 w3 = wlp[(12 | kc) << 6];
        acc[0] = __builtin_amdgcn_mfma_f32_16x16x32_bf16(af, w0, acc[0], 0, 0, 0);
        acc[1] = __builtin_amdgcn_mfma_f32_16x16x32_bf16(af, w1, acc[1], 0, 0, 0);
        acc[2] = __builtin_amdgcn_mfma_f32_16x16x32_bf16(af, w2, acc[2], 0, 0, 0);
        acc[3] = __builtin_amdgcn_mfma_f32_16x16x32_bf16(af, w3, acc[3], 0, 0, 0);
        w0 = wlp[(16 | kc) << 6];
        w1 = wlp[(20 | kc) << 6];
        w2 = wlp[(24 | kc) << 6];
        w3 = wlp[(28 | kc) << 6];
        acc[4] = __builtin_amdgcn_mfma_f32_16x16x32_bf16(af, w0, acc[4], 0, 0, 0);
        acc[5] = __builtin_amdgcn_mfma_f32_16x16x32_bf16(af, w1, acc[5], 0, 0, 0);
        acc[6] = __builtin_amdgcn_mfma_f32_16x16x32_bf16(af, w2, acc[6], 0, 0, 0);
        acc[7] = __builtin_amdgcn_mfma_f32_16x16x32_bf16(af, w3, acc[7], 0, 0, 0);
    }
    __syncthreads();   // done reading tile; reuse as C-tile

    // ---- phase D: epilogue (bias, stats, C via LDS, coalesced stores) ----
    int lr0 = wave * 16 + (quad << 2);
    int gr0 = (b << 7) + lr0;
#pragma unroll
    for (int t = 0; t < 8; ++t) {
        int cch = (t << 4) | m;
        float bc = blds[cch];
        float s = 0.f, q = 0.f;
#pragma unroll
        for (int r = 0; r < 4; ++r) {
            float v = acc[t][r] + bc;
            shA.tile[(lr0 + r) * TSTR + cch] = f2bf(v);
            if (gr0 + r < M) { s += v; q += v * v; }
        }
        s += __shfl_xor(s, 16); s += __shfl_xor(s, 32);
        q += __shfl_xor(q, 16); q += __shfl_xor(q, 32);
        if (quad == 0) { psum[wave * D + cch] = s; psq[wave * D + cch] = q; }
    }
    __syncthreads();

    int mrow = M - (b << 7);
#pragma unroll
    for (int i = 0; i < 4; ++i) {
        int idx = (i << 9) + tid;
        int row = idx >> 4, ch8 = (idx & 15) << 3;
        if (row < mrow) {
            float4 v = *(const float4*)&shA.tile[row * TSTR + ch8];
            *(float4*)(O + (((size_t)(b << 7) + row) << 7) + ch8) = v;
        }
    }
    if (tid < D) {
        float s = 0.f, q = 0.f;
#pragma unroll
        for (int w = 0; w < 8; ++w) { s += psum[w * D + tid]; q += psq[w * D + tid]; }
        float* st = stats + ((b & 7) << 8);
        atomicAdd(&st[tid], s);
        atomicAdd(&st[D + tid], q);
    }
}

// ---------------- GEMM2: BN1+ReLU on the fly -> @W + b, in-place, + stats2 ---------
// XCD-aligned remap (kept from round 5: ~-2 us/dispatch): bucket%8 == blockIdx%8 so
// the A-read hits the local L2 where aggemm left the y1 tile dirty.
__global__ __launch_bounds__(256, 4) void k_gemm_bn(
        u16* __restrict__ A, const bf16x8* __restrict__ wz,
        const float* __restrict__ bias, const float* __restrict__ stats_in,
        const float* __restrict__ gamma, const float* __restrict__ beta,
        float* __restrict__ stats_out, float invM, int M, int nbuck) {
    int j = blockIdx.x;
    int x = j & 7, n = j >> 3;
    int half = n & 1, q = n >> 1;
    int b = (q << 3) + x;
    if (b >= nbuck) return;
    int rb = (b << 7) + (half << 6);

    __shared__ union { bf16x8 w[2048]; u16 c[64 * CT_STRIDE]; } sh;
    __shared__ float blds[D], s_sc[D], s_sh[D], psum[4 * D], psq[4 * D];
    int tid = threadIdx.x;
    int wave = tid >> 6, lane = tid & 63;
    int m = lane & 15, quad = lane >> 4;
    int row0 = rb + wave * 16;

    const u16* ap = A + (size_t)(row0 + m) * D + (quad << 3);
    ushort4 p[4][2];
#pragma unroll
    for (int kc = 0; kc < 4; ++kc) {
        p[kc][0] = *(const ushort4*)(ap + (kc << 5));
        p[kc][1] = *(const ushort4*)(ap + (kc << 5) + 4);
    }

    for (int i = tid; i < 2048; i += 256) sh.w[i] = wz[i];
    if (tid < D) {
        float s = 0.f, qq = 0.f;
#pragma unroll
        for (int r = 0; r < 8; ++r) {
            s += stats_in[(r << 8) + tid];
            qq += stats_in[(r << 8) + D + tid];
        }
        float mean = s * invM;
        float var = qq * invM - mean * mean;
        float sc = rsqrtf(var + 1e-5f) * gamma[tid];
        s_sc[tid] = sc;
        s_sh[tid] = beta[tid] - mean * sc;
        blds[tid] = bias[tid];
    }
    __syncthreads();

    f32x4 z = {0.f, 0.f, 0.f, 0.f};
    f32x4 acc[8];
#pragma unroll
    for (int t = 0; t < 8; ++t) acc[t] = z;

#pragma unroll
    for (int kc = 0; kc < 4; ++kc) {
        int kb = (kc << 5) | (quad << 3);
        float4 c0 = *(const float4*)&s_sc[kb];
        float4 c1 = *(const float4*)&s_sc[kb + 4];
        float4 h0 = *(const float4*)&s_sh[kb];
        float4 h1 = *(const float4*)&s_sh[kb + 4];
        ushort4 p0 = p[kc][0], p1 = p[kc][1];
        bf16x8 af;
        af[0] = (__bf16)fmaxf(0.f, fmaf(bf2f(p0.x), c0.x, h0.x));
        af[1] = (__bf16)fmaxf(0.f, fmaf(bf2f(p0.y), c0.y, h0.y));
        af[2] = (__bf16)fmaxf(0.f, fmaf(bf2f(p0.z), c0.z, h0.z));
        af[3] = (__bf16)fmaxf(0.f, fmaf(bf2f(p0.w), c0.w, h0.w));
        af[4] = (__bf16)fmaxf(0.f, fmaf(bf2f(p1.x), c1.x, h1.x));
        af[5] = (__bf16)fmaxf(0.f, fmaf(bf2f(p1.y), c1.y, h1.y));
        af[6] = (__bf16)fmaxf(0.f, fmaf(bf2f(p1.z), c1.z, h1.z));
        af[7] = (__bf16)fmaxf(0.f, fmaf(bf2f(p1.w), c1.w, h1.w));
#pragma unroll
        for (int t = 0; t < 8; ++t)
            acc[t] = __builtin_amdgcn_mfma_f32_16x16x32_bf16(
                af, sh.w[(((t << 2) | kc) << 6) | lane], acc[t], 0, 0, 0);
    }
    __syncthreads();

    int lr0 = wave * 16 + (quad << 2);
    int gr0 = rb + lr0;
#pragma unroll
    for (int t = 0; t < 8; ++t) {
        int cch = (t << 4) | m;
        float bc = blds[cch];
        float s = 0.f, qq = 0.f;
#pragma unroll
        for (int r = 0; r < 4; ++r) {
            float v = acc[t][r] + bc;
            sh.c[(lr0 + r) * CT_STRIDE + cch] = f2bf(v);
            if (gr0 + r < M) { s += v; qq += v * v; }
        }
        s += __shfl_xor(s, 16); s += __shfl_xor(s, 32);
        qq += __shfl_xor(qq, 16); qq += __shfl_xor(qq, 32);
        if (quad == 0) { psum[wave * D + cch] = s; psq[wave * D + cch] = qq; }
    }
    __syncthreads();

    int mrow = M - rb;
#pragma unroll
    for (int i = 0; i < 4; ++i) {
        int idx = (i << 8) + tid;
        int row = idx >> 4, ch8 = (idx & 15) << 3;
        if (row < mrow) {
            float4 v = *(const float4*)&sh.c[row * CT_STRIDE + ch8];
            *(float4*)(A + ((size_t)(rb + row) << 7) + ch8) = v;
        }
    }
    if (tid < D) {
        float s = psum[tid] + psum[D + tid] + psum[2 * D + tid] + psum[3 * D + tid];
        float qq = psq[tid] + psq[D + tid] + psq[2 * D + tid] + psq[3 * D + tid];
        float* st = stats_out + (x << 8);
        atomicAdd(&st[tid], s);
        atomicAdd(&st[D + tid], qq);
    }
}

// ---------- BN2+ReLU -> h (bufH), + per-graph pooling with ZERO atomics ------------
__device__ __forceinline__ void bnrow(const u16* __restrict__ y,
                                      u16* __restrict__ hout, size_t row, int c,
                                      float4 sc4, float4 sh4, int writeh,
                                      float& a0, float& a1, float& a2, float& a3) {
    ushort4 u = *(const ushort4*)(y + (row << 7) + c);
    float h0 = fmaxf(0.f, fmaf(bf2f(u.x), sc4.x, sh4.x));
    float h1 = fmaxf(0.f, fmaf(bf2f(u.y), sc4.y, sh4.y));
    float h2 = fmaxf(0.f, fmaf(bf2f(u.z), sc4.z, sh4.z));
    float h3 = fmaxf(0.f, fmaf(bf2f(u.w), sc4.w, sh4.w));
    if (writeh) {
        ushort4 o;
        o.x = f2bf(h0); o.y = f2bf(h1); o.z = f2bf(h2); o.w = f2bf(h3);
        *(ushort4*)(hout + (row << 7) + c) = o;
    }
    a0 += h0; a1 += h1; a2 += h2; a3 += h3;
}

template<int WRITEH>
__global__ __launch_bounds__(512) void k_bnpool(
        const u16* __restrict__ y, const float* __restrict__ stats,
        const float* __restrict__ gamma, const float* __restrict__ beta,
        const int* __restrict__ gptr, const float* __restrict__ fw,
        int layer, u16* __restrict__ hout, float* __restrict__ gacc, float invM) {
    __shared__ float s_sc[D], s_sh[D];
    __shared__ float red[16 * D];
    int t = threadIdx.x;
    if (t < D) {
        float s = 0.f, q = 0.f;
#pragma unroll
        for (int r = 0; r < 8; ++r) {
            s += stats[(r << 8) + t];
            q += stats[(r << 8) + D + t];
        }
        float mean = s * invM;
        float sv = rsqrtf(q * invM - mean * mean + 1e-5f) * gamma[t];
        s_sc[t] = sv;
        s_sh[t] = beta[t] - mean * sv;
    }
    __syncthreads();

    int g = blockIdx.x;
    int n0 = gptr[g], n1 = gptr[g + 1];
    int c = (t & 31) << 2;
    int rg = t >> 5;                    // 16 row-groups, rows stride 16
    float4 sc4 = *(const float4*)&s_sc[c];
    float4 sh4 = *(const float4*)&s_sh[c];

    float a0 = 0.f, a1 = 0.f, a2 = 0.f, a3 = 0.f;
    int r = n0 + rg;
    for (; r + 48 < n1; r += 64) {      // 4 rows in flight per thread
        bnrow(y, hout, (size_t)r,        c, sc4, sh4, WRITEH, a0, a1, a2, a3);
        bnrow(y, hout, (size_t)(r + 16), c, sc4, sh4, WRITEH, a0, a1, a2, a3);
        bnrow(y, hout, (size_t)(r + 32), c, sc4, sh4, WRITEH, a0, a1, a2, a3);
        bnrow(y, hout, (size_t)(r + 48), c, sc4, sh4, WRITEH, a0, a1, a2, a3);
    }
    for (; r < n1; r += 16)
        bnrow(y, hout, (size_t)r, c, sc4, sh4, WRITEH, a0, a1, a2, a3);

    *(float4*)&red[rg * D + c] = make_float4(a0, a1, a2, a3);
    __syncthreads();

    if (t < D) {
        float s = 0.f;
#pragma unroll
        for (int w = 0; w < 16; ++w) s += red[w * D + t];
        gacc[((size_t)g << 7) + t] += fw[layer] * s;
    }
}

// ---------------- final: out = gacc(Gx128) @ Wp(128x10) + bp ----------------
__global__ void k_final(const float* __restrict__ gacc, const float* __restrict__ Wp,
                        const float* __restrict__ bp, float* __restrict__ out) {
    __shared__ float w[D * DOUT];
    __shared__ float bb[DOUT];
    int t = threadIdx.x;
    for (int i = t; i < D * DOUT; i += blockDim.x) w[i] = Wp[i];
    if (t < DOUT) bb[t] = bp[t];
    __syncthreads();
    float acc[DOUT];
#pragma unroll
    for (int o = 0; o < DOUT; ++o) acc[o] = bb[o];
    for (int k = 0; k < D; ++k) {
        float a = gacc[(size_t)t * D + k];
#pragma unroll
        for (int o = 0; o < DOUT; ++o) acc[o] += a * w[k * DOUT + o];
    }
#pragma unroll
    for (int o = 0; o < DOUT; ++o) out[(size_t)t * DOUT + o] = acc[o];
}

extern "C" void kernel_launch(void* const* d_in, const int* in_sizes, int n_in,
                              void* d_out, int out_size, void* d_ws, size_t ws_size,
                              hipStream_t stream) {
    const float* x    = (const float*)d_in[0];
    const int* esrc   = (const int*)d_in[1];
    const int* edst   = (const int*)d_in[2];
    const int* gids   = (const int*)d_in[3];
    const float* eps  = (const float*)d_in[4];
    const float* fw   = (const float*)d_in[5];
    const float* W1   = (const float*)d_in[6];
    const float* b1   = (const float*)d_in[7];
    const float* g1   = (const float*)d_in[8];
    const float* bt1  = (const float*)d_in[9];
    const float* W2   = (const float*)d_in[10];
    const float* b2   = (const float*)d_in[11];
    const float* g2   = (const float*)d_in[12];
    const float* bt2  = (const float*)d_in[13];
    const float* Wp   = (const float*)d_in[14];
    const float* bp   = (const float*)d_in[15];
    float* out        = (float*)d_out;

    const int M = in_sizes[3];     // 100000 nodes
    const int E = in_sizes[1];     // 1600000 edges
    const int L = in_sizes[4];     // 4 layers
    const int G = out_size / DOUT; // 256 graphs
    const int nb  = (M + 127) >> 7;           // buckets of 128 dst nodes (782)
    const int Mpad = nb << 7;
    const int nbk = (E + 2047) >> 11;         // 2K-edge chunks (782)
    const float invM = 1.0f / (float)M;

    char* ws = (char*)d_ws;
    u16* bufT  = (u16*)ws;  ws += (size_t)Mpad * D * 2;   // y1 -> y2 (in-place MLP)
    u16* bufH  = (u16*)ws;  ws += (size_t)Mpad * D * 2;   // hidden bf16 (gather src)
    int* pairs = (int*)ws;  ws += (size_t)nb * 4096 * 4;  // packed pairs -> CSR edges
    int* cnts  = (int*)ws;  ws += (size_t)nbk * 1024 * 4; // per-(chunk,bucket) bases
    int* btot  = (int*)ws;  ws += 1024 * 4;               // bucket totals
    int* gptr  = (int*)ws;  ws += 512 * 4;                // graph segment offsets
    int* gmeta = (int*)ws;  ws += (size_t)nb * 256 * 4;   // per-bucket lcnt|loff
    bf16x8* wswz = (bf16x8*)ws; ws += (size_t)2 * L * 2048 * 16;  // swizzled W
    // contiguous zero region: stats (8 replicas) | gacc
    float* stats = (float*)ws; ws += (size_t)L * 4096 * 4;
    float* gacc  = (float*)ws; ws += (size_t)G * D * 4;

    int zbytes = L * 4096 * 4 + G * D * 4;
    int n4 = zbytes / 16;
    k_zero<<<(n4 + 255) / 256, 256, 0, stream>>>((float4*)stats, n4);

    k_prepw<<<2 * L * 8, 256, 0, stream>>>(W1, W2, wswz, L);
    k_hist<<<nbk, 256, 0, stream>>>(edst, cnts, E, nb);
    k_off<<<(nb + 3) / 4, 256, 0, stream>>>(cnts, btot, nbk, nb);
    k_scat<<<nbk, 256, 0, stream>>>(esrc, edst, cnts, pairs, E, nb);
    k_csr<<<nb, 256, 0, stream>>>(btot, pairs, gmeta);   // in-place CSR sort
    k_gseg<<<1, 512, 0, stream>>>(gids, gptr, M, G);
    k_cvt<<<(Mpad * (D / 4) + 255) / 256, 256, 0, stream>>>(x, bufH, M, Mpad);

    int nbR = (nb + 7) & ~7;          // XCD-aligned gemm_bn grid: 2 halves per bucket
    for (int l = 0; l < L; ++l) {
        float* st1 = stats + (size_t)l * 4096;
        float* st2 = st1 + 2048;
        k_aggemm<<<nb, 512, 0, stream>>>(bufH, pairs, gmeta, btot, eps, l,
                                         wswz + (size_t)l * 2048, b1 + (size_t)l * D,
                                         bufT, st1, M);
        k_gemm_bn<<<nbR * 2, 256, 0, stream>>>(bufT, wswz + (size_t)(L + l) * 2048,
                                               b2 + (size_t)l * D, st1,
                                               g1 + (size_t)l * D, bt1 + (size_t)l * D,
                                               st2, invM, M, nb);
        if (l < L - 1)
            k_bnpool<1><<<G, 512, 0, stream>>>(bufT, st2, g2 + (size_t)l * D,
                                               bt2 + (size_t)l * D, gptr, fw, l,
                                               bufH, gacc, invM);
        else
            k_bnpool<0><<<G, 512, 0, stream>>>(bufT, st2, g2 + (size_t)l * D,
                                               bt2 + (size_t)l * D, gptr, fw, l,
                                               bufH, gacc, invM);
    }
    k_final<<<1, G, 0, stream>>>(gacc, Wp, bp, out);
}